// Round 5
// baseline (421.852 us; speedup 1.0000x reference)
//
#include <hip/hip_runtime.h>

// out[b,d,t] = sum_c x[b,c,t] * weights[subjects[b],c,d]
// B=256, C=270, T=1024, NSUB=200. fp32 in/out, bf16 MFMA internally.
// NO LDS, NO barriers: each wave loads its MFMA fragments directly from
// global (coalesced 64B segments per 16-lane group), packs with
// v_cvt_pk_bf16_f32. B (x) depth-2 register pipeline, A (w) depth-1.
// d-overflow lanes use clamped addresses: garbage flows only into D-rows
// that the guarded store discards.

#define C_    270
#define T_    1024
#define B_    256
#define NSUB_ 200
#define BM 96      // d-tile
#define BN 128     // t-tile

typedef __attribute__((ext_vector_type(8))) short bf16x8;
typedef __attribute__((ext_vector_type(4))) float f32x4;
typedef __attribute__((ext_vector_type(4))) int i32x4;

__device__ __forceinline__ unsigned pk(float lo, float hi) {
    // v_cvt_pk_bf16_f32: RNE, lo -> low 16 bits. No builtin on gfx950.
    unsigned r;
    asm("v_cvt_pk_bf16_f32 %0, %1, %2" : "=v"(r) : "v"(lo), "v"(hi));
    return r;
}

struct LoadsB { float v[4][8]; };  // [n-frag][k] f32 in flight
struct LoadsA { float v[3][8]; };  // [m-frag][k]
struct Frags  { bf16x8 b[4]; bf16x8 a[3]; };

__global__ __launch_bounds__(256, 2)
void subj_layers_kernel(const float* __restrict__ x,
                        const int* __restrict__ subjects,
                        const float* __restrict__ w,
                        float* __restrict__ out)
{
    const int tid  = threadIdx.x;
    const int lane = tid & 63;
    const int wid  = tid >> 6;
    const int wr   = wid >> 1;   // wave d-row 0..1
    const int wc   = wid & 1;    // wave t-col 0..1
    const int lg   = lane >> 4;  // c-oct selector
    const int lr   = lane & 15;

    // Bijective XCD-chunk swizzle (6144 = 8 x 768), d-tile fastest.
    const int bid  = (blockIdx.x & 7) * 768 + (blockIdx.x >> 3);
    const int b    = bid / 24;
    const int rem  = bid % 24;
    const int d0   = (rem % 3) * BM;   // 0,96,192
    const int t0   = (rem / 3) * BN;   // 0..896

    int sub = subjects[b];
    sub = sub < 0 ? 0 : (sub >= NSUB_ ? NSUB_ - 1 : sub);
    const float* __restrict__ wsub = w + (size_t)sub * (C_ * C_);

    // Per-lane column base pointers.
    // B: lane reads x[c][tcol], tcol = t0 + wc*64 + n*16 + lr  (n via +16)
    const float* __restrict__ xcol = x + (size_t)b * (C_ * T_) + t0 + wc * 64 + lr;
    // A: lane reads w[c][dcol_m], dcol clamped (OOB rows discarded at store)
    const float* wcol[3];
    #pragma unroll
    for (int m = 0; m < 3; ++m) {
        int d = d0 + wr * 48 + m * 16 + lr;
        if (d > C_ - 1) d = C_ - 1;
        wcol[m] = wsub + d;
    }

    f32x4 acc[3][4];
    #pragma unroll
    for (int m = 0; m < 3; ++m)
        #pragma unroll
        for (int n = 0; n < 4; ++n)
            acc[m][n] = (f32x4){0.f, 0.f, 0.f, 0.f};

    auto loadB = [&](int c0, LoadsB& L, bool full) {
        #pragma unroll
        for (int n = 0; n < 4; ++n)
            #pragma unroll
            for (int j = 0; j < 8; ++j) {
                const int c = c0 + 8 * lg + j;
                L.v[n][j] = (full || c < C_) ? xcol[(size_t)c * T_ + n * 16] : 0.f;
            }
    };
    auto loadA = [&](int c0, LoadsA& L, bool full) {
        #pragma unroll
        for (int m = 0; m < 3; ++m)
            #pragma unroll
            for (int j = 0; j < 8; ++j) {
                const int c = c0 + 8 * lg + j;
                L.v[m][j] = (full || c < C_) ? wcol[m][(size_t)c * C_] : 0.f;
            }
    };
    auto cvt = [&](const LoadsB& LB, const LoadsA& LA, Frags& F) {
        #pragma unroll
        for (int n = 0; n < 4; ++n) {
            i32x4 u;
            #pragma unroll
            for (int p = 0; p < 4; ++p)
                u[p] = (int)pk(LB.v[n][2 * p], LB.v[n][2 * p + 1]);
            F.b[n] = __builtin_bit_cast(bf16x8, u);
        }
        #pragma unroll
        for (int m = 0; m < 3; ++m) {
            i32x4 u;
            #pragma unroll
            for (int p = 0; p < 4; ++p)
                u[p] = (int)pk(LA.v[m][2 * p], LA.v[m][2 * p + 1]);
            F.a[m] = __builtin_bit_cast(bf16x8, u);
        }
    };
    auto compute = [&](const Frags& F) {
        #pragma unroll
        for (int m = 0; m < 3; ++m)
            #pragma unroll
            for (int n = 0; n < 4; ++n)
                acc[m][n] = __builtin_amdgcn_mfma_f32_16x16x32_bf16(F.a[m], F.b[n], acc[m][n], 0, 0, 0);
    };

    // ---- register pipeline: B depth-2 (two slots), A depth-1 (one slot) ----
    LoadsB LB0, LB1;
    LoadsA LA;
    Frags  F0, F1;

    // prologue: steps 0,1 in flight
    loadB(0, LB0, true);
    loadA(0, LA, true);
    loadB(32, LB1, true);
    cvt(LB0, LA, F0);          // step-0 frags (waits on step-0 loads)
    loadA(32, LA, true);       // step-1 A (overwrites after read)

    // bodies: step s computes F, converts s+1, issues loads for s+2
    #pragma unroll 1
    for (int kk = 0; kk < 3; ++kk) {
        // even step s = 2kk: loads -> slot0
        loadB(64 * kk + 64, LB0, true);
        compute(F0);
        cvt(LB1, LA, F1);
        loadA(64 * kk + 64, LA, true);
        // odd step s = 2kk+1: loads -> slot1
        loadB(64 * kk + 96, LB1, true);
        compute(F1);
        cvt(LB0, LA, F0);
        loadA(64 * kk + 96, LA, true);
    }
    // peeled: step 6 (issues guarded step-8 loads), step 7, step 8
    loadB(256, LB0, false);
    compute(F0);               // step 6
    cvt(LB1, LA, F1);
    loadA(256, LA, false);
    compute(F1);               // step 7
    cvt(LB0, LA, F0);
    compute(F0);               // step 8

    // ---- epilogue: C/D layout col=lane&15, row=(lane>>4)*4+reg ----
    float* outb = out + (size_t)b * (C_ * T_);
    #pragma unroll
    for (int m = 0; m < 3; ++m) {
        const int dbase = d0 + wr * 48 + m * 16 + 4 * lg;
        #pragma unroll
        for (int n = 0; n < 4; ++n) {
            const int t = t0 + wc * 64 + n * 16 + lr;
            #pragma unroll
            for (int rr = 0; rr < 4; ++rr) {
                const int d = dbase + rr;
                if (d < C_)
                    outb[(size_t)d * T_ + t] = acc[m][n][rr];
            }
        }
    }
}

extern "C" void kernel_launch(void* const* d_in, const int* in_sizes, int n_in,
                              void* d_out, int out_size, void* d_ws, size_t ws_size,
                              hipStream_t stream)
{
    const float* x        = (const float*)d_in[0];
    const int*   subjects = (const int*)d_in[1];
    const float* w        = (const float*)d_in[2];
    float* out            = (float*)d_out;

    dim3 grid(B_ * 24);  // 256 batches * (3 d-tiles * 8 t-tiles)
    dim3 block(256);
    hipLaunchKernelGGL(subj_layers_kernel, grid, block, 0, stream,
                       x, subjects, w, out);
}